// Round 24
// baseline (191.171 us; speedup 1.0000x reference)
//
#include <hip/hip_runtime.h>
#include <cstdint>
#include <cstddef>

#define T_ 2048
#define D_ 2048
#define E_ 16
#define F_ 512

typedef unsigned short u16;
typedef unsigned int u32;
typedef unsigned long long u64;
typedef __attribute__((ext_vector_type(8))) short bf16x8;
typedef __attribute__((ext_vector_type(4))) float f32x4;
typedef __attribute__((ext_vector_type(2))) u32 u32x2;
typedef __attribute__((ext_vector_type(4))) u32 u32x4;
typedef __attribute__((ext_vector_type(8))) u16 u16x8;
typedef __attribute__((ext_vector_type(4))) u16 u16x4;

__device__ __forceinline__ u16 f2bf(float f){
  union { float f; u32 u; } c; c.f = f;
  return (u16)((c.u + 0x7FFFu + ((c.u >> 16) & 1u)) >> 16);
}

__device__ __forceinline__ float b2f(u16 v){
  union { u32 u; float f; } c; c.u = (u32)v << 16;
  return c.f;
}

__device__ __forceinline__ void gload16(const void* g, void* l){
  __builtin_amdgcn_global_load_lds((const __attribute__((address_space(1))) void*)g,
                                   (__attribute__((address_space(3))) void*)l,
                                   16, 0, 0);
}

__device__ __forceinline__ u32 pk2(float a, float b){
  u32 r;
  asm("v_cvt_pk_bf16_f32 %0, %1, %2" : "=v"(r) : "v"(a), "v"(b));
  return r;
}

// ---------------- K1: rmsnorm + router (fp32); writes per-token top4 ----------------
__global__ __launch_bounds__(256) void k_norm_router(
    const float* __restrict__ x, const float* __restrict__ nw, const float* __restrict__ gw,
    u16* __restrict__ h, int* __restrict__ tok_e, float* __restrict__ tok_w)
{
  const int t = blockIdx.x, tid = threadIdx.x;
  const int lane = tid & 63, wid = tid >> 6;
  const int d0 = tid * 8;
  const float4 v0 = *(const float4*)(x + (size_t)t*D_ + d0);
  const float4 v1 = *(const float4*)(x + (size_t)t*D_ + d0 + 4);
  float hv[8] = {v0.x, v0.y, v0.z, v0.w, v1.x, v1.y, v1.z, v1.w};
  float ss = 0.f;
  #pragma unroll
  for (int j = 0; j < 8; ++j) ss += hv[j]*hv[j];
  #pragma unroll
  for (int o = 32; o; o >>= 1) ss += __shfl_xor(ss, o);
  __shared__ float sred[4];
  __shared__ float red16[4][16];
  __shared__ float lf[16];
  if (lane == 0) sred[wid] = ss;
  __syncthreads();
  const float rstd = rsqrtf((sred[0]+sred[1]+sred[2]+sred[3]) * (1.f/(float)D_) + 1e-6f);
  const float4 w0 = *(const float4*)(nw + d0);
  const float4 w1 = *(const float4*)(nw + d0 + 4);
  const float wv[8] = {w0.x,w0.y,w0.z,w0.w,w1.x,w1.y,w1.z,w1.w};
  #pragma unroll
  for (int j = 0; j < 8; ++j) hv[j] = hv[j] * rstd * wv[j];
  u16x8 hb;
  #pragma unroll
  for (int j = 0; j < 8; ++j) hb[j] = f2bf(hv[j]);
  *(u16x8*)(h + (size_t)t*D_ + d0) = hb;

  float lg[16];
  #pragma unroll
  for (int e = 0; e < 16; ++e){
    const float4 g0 = *(const float4*)(gw + e*D_ + d0);
    const float4 g1 = *(const float4*)(gw + e*D_ + d0 + 4);
    lg[e] = hv[0]*g0.x + hv[1]*g0.y + hv[2]*g0.z + hv[3]*g0.w
          + hv[4]*g1.x + hv[5]*g1.y + hv[6]*g1.z + hv[7]*g1.w;
  }
  #pragma unroll
  for (int e = 0; e < 16; ++e){
    #pragma unroll
    for (int o = 32; o; o >>= 1) lg[e] += __shfl_xor(lg[e], o);
  }
  if (lane == 0){
    #pragma unroll
    for (int e = 0; e < 16; ++e) red16[wid][e] = lg[e];
  }
  __syncthreads();
  if (tid < 16) lf[tid] = red16[0][tid] + red16[1][tid] + red16[2][tid] + red16[3][tid];
  __syncthreads();
  if (tid == 0){
    float l[16];
    #pragma unroll
    for (int e = 0; e < 16; ++e) l[e] = lf[e];
    int sel[4]; float sv[4]; u32 used = 0;
    for (int k = 0; k < 4; ++k){
      float b = -3.4e38f; int bi = 0;
      for (int e = 0; e < 16; ++e)
        if (!((used >> e) & 1u) && l[e] > b){ b = l[e]; bi = e; }
      used |= 1u << bi; sel[k] = bi; sv[k] = b;
    }
    float ex[4]; float s = 0.f;
    for (int k = 0; k < 4; ++k){ ex[k] = __expf(sv[k] - sv[0]); s += ex[k]; }
    const float inv = 1.f / s;
    int4 te = {sel[0], sel[1], sel[2], sel[3]};
    float4 tw4 = {ex[0]*inv, ex[1]*inv, ex[2]*inv, ex[3]*inv};
    *(int4*)(tok_e + t*4) = te;
    *(float4*)(tok_w + t*4) = tw4;
  }
}

// ---------------- K2: build per-expert token lists (deterministic compaction) ----------------
__global__ __launch_bounds__(256) void k_build_lists(
    const int* __restrict__ tok_e, const float* __restrict__ tok_w,
    int* __restrict__ eidx, float* __restrict__ ew, int* __restrict__ counts)
{
  const int e = blockIdx.x, tid = threadIdx.x;
  const int lane = tid & 63, wid = tid >> 6;
  __shared__ int wtot[4];
  __shared__ int base;
  if (tid == 0) base = 0;
  __syncthreads();
  for (int t0 = 0; t0 < T_; t0 += 256){
    const int t = t0 + tid;
    const int4 te = *(const int4*)(tok_e + t*4);
    const float4 tw = *(const float4*)(tok_w + t*4);
    bool m = false; float wv = 0.f;
    if      (te.x == e){ m = true; wv = tw.x; }
    else if (te.y == e){ m = true; wv = tw.y; }
    else if (te.z == e){ m = true; wv = tw.z; }
    else if (te.w == e){ m = true; wv = tw.w; }
    const u64 mask = __ballot(m);
    const int pre = __popcll(mask & ((1ull << lane) - 1ull));
    if (lane == 0) wtot[wid] = __popcll(mask);
    __syncthreads();
    int wbase = base;
    for (int i = 0; i < wid; ++i) wbase += wtot[i];
    if (m){
      eidx[e*T_ + wbase + pre] = t;
      ew[e*T_ + wbase + pre] = wv;
    }
    __syncthreads();
    if (tid == 0) base += wtot[0] + wtot[1] + wtot[2] + wtot[3];
    __syncthreads();
  }
  if (tid == 0) counts[e] = base;
}

// ---------------- K2b: invert lists -> per-token slot ids + per-slot weight ----------------
__global__ __launch_bounds__(256) void k_slots(
    const int* __restrict__ counts, const int* __restrict__ eidx,
    const float* __restrict__ ew, const int* __restrict__ tok_e,
    int* __restrict__ tok_slot, float* __restrict__ sw)
{
  const int e = blockIdx.x;
  int abase = 0;
  for (int i = 0; i < e; ++i) abase += counts[i];
  const int cnt = counts[e];
  for (int s = threadIdx.x; s < cnt; s += 256){
    const int t = eidx[e*T_ + s];
    const int4 te = *(const int4*)(tok_e + t*4);
    const int kidx = (te.x == e) ? 0 : (te.y == e) ? 1 : (te.z == e) ? 2 : 3;
    tok_slot[t*4 + kidx] = abase + s;
    sw[abase + s] = ew[e*T_ + s];
  }
}

// -------- gateup W staging: thread -> 4 rows x 4 k (one float4 per k) --------
#define WLOADG(KB, SRC, S) do {                                                \
    _Pragma("unroll")                                                          \
    for (int j = 0; j < 4; ++j){                                               \
      const float4 t_ = *(const float4*)((SRC) + (size_t)((KB) + ko*4 + j)*(S));\
      wvf[0][j]=t_.x; wvf[1][j]=t_.y; wvf[2][j]=t_.z; wvf[3][j]=t_.w;          \
    }                                                                          \
  } while (0)

#define WSTOREG(WP) do {                                                       \
    _Pragma("unroll")                                                          \
    for (int i = 0; i < 4; ++i){                                               \
      const int r_ = rg4*4 + i;                                                \
      const u32 idx_ = (u32)(r_*32 + ((ko>>1) ^ (r_&3) ^ ((r_>>2)&3))*8 + (ko&1)*4); \
      u32x2 o_ = { pk2(wvf[i][0], wvf[i][1]), pk2(wvf[i][2], wvf[i][3]) };     \
      *(u32x2*)&(WP)[idx_] = o_;                                               \
    }                                                                          \
  } while (0)

// -------- down W staging: thread -> 4 rows x 2 k --------
#define WLOADD(KB, SRC, S) do {                                                \
    _Pragma("unroll")                                                          \
    for (int j = 0; j < 2; ++j){                                               \
      const float4 t_ = *(const float4*)((SRC) + (size_t)((KB) + ko*2 + j)*(S));\
      wvf[0][j]=t_.x; wvf[1][j]=t_.y; wvf[2][j]=t_.z; wvf[3][j]=t_.w;          \
    }                                                                          \
  } while (0)

#define WSTORED(WP) do {                                                       \
    _Pragma("unroll")                                                          \
    for (int i = 0; i < 4; ++i){                                               \
      const int r_ = rg4*4 + i;                                                \
      const u32 idx_ = (u32)(r_*32 + ((ko>>2) ^ (r_&3) ^ ((r_>>2)&3))*8 + (ko&3)*2); \
      *(u32*)&(WP)[idx_] = pk2(wvf[i][0], wvf[i][1]);                          \
    }                                                                          \
  } while (0)

// ---------------- K3: gate/up GEMM split-K=2 (256 tok x 64F, K-half 1024, BK=32) ----------------
// grid 2048: bid = tt*256 + e*16 + ft*2 + kh (tt slowest). 256 thr / 4 waves, wave 64x128, acc 4x8.
// Writes raw bf16 partials to pbuf[kh][slot][0..511 gate | 512..1023 up]. 64KB LDS, 2 blk/CU.
__global__ __launch_bounds__(256, 2) void k_gateup(
    const u16* __restrict__ h, const float* __restrict__ wg, const float* __restrict__ wu,
    const int* __restrict__ counts, const int* __restrict__ eidx,
    u16* __restrict__ pbuf)
{
  const int bid = blockIdx.x;
  const int tt = bid >> 8;
  const int e  = (bid >> 4) & 15;
  const int ft = (bid >> 1) & 7;
  const int kh = bid & 1;

  const int cnt = counts[e];
  const int row0 = tt * 256;
  if (row0 >= cnt) return;
  int abase = 0;
  for (int i = 0; i < e; ++i) abase += counts[i];

  const int tid = threadIdx.x, lane = tid & 63, w = tid >> 6;
  const int f0 = ft * 64;
  const int kbase = kh * 1024;

  __shared__ __align__(16) u16 Xs[3][8192];   // [stage][256 rows x 32 k] 16KB each
  __shared__ __align__(16) u16 Ws[2][4096];   // [buf][rows 0..63 gate, 64..127 up] 8KB each

  int* toksS = (int*)&Xs[0][0];
  if (tid < 256){
    const int slot = row0 + tid;
    const int cs = slot < cnt ? slot : (cnt - 1);
    toksS[tid] = eidx[e*T_ + cs];
  }
  __syncthreads();

  // X staging: wave w stages rows [w*64, +64); 4 instr x 16 rows; lane -> row lane>>2, chunk lane&3
  const int lr = lane >> 2, lc = lane & 3;
  const int csw = lc ^ (lr & 3) ^ ((lr >> 2) & 3);
  const u16* srcX[4]; u32 dof[4];
  #pragma unroll
  for (int q = 0; q < 4; ++q){
    const int r = w*64 + q*16 + lr;
    srcX[q] = h + (size_t)toksS[r]*D_ + kbase + 8*csw;
    dof[q] = (u32)((w*64 + q*16) * 32);
  }
  // W staging: rg4 = tid&31 -> rows rg4*4..+3 (gate rg4<16, else up); ko = tid>>5 (0..7) -> 4 k's
  const int rg4 = tid & 31, ko = tid >> 5;
  const float* wsel = (rg4 < 16) ? wg : wu;
  const float* srcWf = wsel + (size_t)e*D_*F_ + (size_t)kbase*F_ + f0 + ((rg4*4) & 63);
  __syncthreads();   // done with toks overlay

  const int p = lane & 15, g4 = lane >> 4;
  u32 aB[4], bB[8];
  #pragma unroll
  for (int m = 0; m < 4; ++m) aB[m] = (u32)((w*64 + m*16 + p) * 32);
  #pragma unroll
  for (int n = 0; n < 8; ++n) bB[n] = (u32)((n*16 + p) * 32);
  const u32 s8 = 8u * (u32)(g4 ^ (p & 3) ^ ((p >> 2) & 3));

  f32x4 acc[4][8] = {};
  float wvf[4][4];

  // prologue: W0(4); X0(4); X1(4); vmcnt(8) retires W0; store W0; vmcnt(4) retires X0.
  WLOADG(0, srcWf, F_);
  #pragma unroll
  for (int q = 0; q < 4; ++q) gload16(srcX[q],      (void*)&Xs[0][dof[q]]);
  #pragma unroll
  for (int q = 0; q < 4; ++q) gload16(srcX[q] + 32, (void*)&Xs[1][dof[q]]);
  asm volatile("s_waitcnt vmcnt(8)" ::: "memory");
  __builtin_amdgcn_sched_barrier(0);
  WSTOREG(&Ws[0][0]);
  asm volatile("s_waitcnt vmcnt(4)" ::: "memory");

  const int NSTEP = 1024 / 32;   // 32
  int xc = 0;
  for (int kt = 0; kt < NSTEP; ++kt){
    asm volatile("s_waitcnt lgkmcnt(0)" ::: "memory");
    __builtin_amdgcn_s_barrier();
    __builtin_amdgcn_sched_barrier(0);
    if (kt + 1 < NSTEP){
      WLOADG((kt + 1) * 32, srcWf, F_);
      __builtin_amdgcn_sched_barrier(0);
    }
    {
      const u16* Xp = &Xs[xc][0];
      const u16* Wp = &Ws[kt & 1][0];
      bf16x8 aF[4], bF[8];
      #pragma unroll
      for (int m = 0; m < 4; ++m) aF[m] = *(const bf16x8*)&Xp[aB[m] + s8];
      #pragma unroll
      for (int n = 0; n < 8; ++n) bF[n] = *(const bf16x8*)&Wp[bB[n] + s8];
      #pragma unroll
      for (int m = 0; m < 4; ++m)
        #pragma unroll
        for (int n = 0; n < 8; ++n)
          acc[m][n] = __builtin_amdgcn_mfma_f32_16x16x32_bf16(aF[m], bF[n], acc[m][n], 0, 0, 0);
    }
    if (kt + 2 < NSTEP){
      const int kb2 = (kt + 2) * 32;
      int nb = xc + 2; if (nb >= 3) nb -= 3;
      #pragma unroll
      for (int q = 0; q < 4; ++q) gload16(srcX[q] + kb2, (void*)&Xs[nb][dof[q]]);
    }
    if (kt + 1 < NSTEP){
      if (kt + 2 < NSTEP) asm volatile("s_waitcnt vmcnt(4)" ::: "memory");
      else                asm volatile("s_waitcnt vmcnt(0)" ::: "memory");
      __builtin_amdgcn_sched_barrier(0);
      WSTOREG(&Ws[(kt + 1) & 1][0]);
    }
    xc = (xc == 2) ? 0 : xc + 1;
  }

  // epilogue: raw partials (no tw/silu) -> pbuf[kh][abase+slot][f0.. | 512+f0..]
  u16* pb = pbuf + ((size_t)kh * 8192 + (size_t)abase) * 1024;
  #pragma unroll
  for (int m = 0; m < 4; ++m)
    #pragma unroll
    for (int r = 0; r < 4; ++r){
      const int row  = w*64 + m*16 + g4*4 + r;
      const int slot = row0 + row;
      if (slot < cnt){
        u16* pr = pb + (size_t)slot*1024 + f0;
        #pragma unroll
        for (int n = 0; n < 4; ++n){
          pr[n*16 + p]       = f2bf(acc[m][n][r]);
          pr[512 + n*16 + p] = f2bf(acc[m][n+4][r]);
        }
      }
    }
}

// ---------------- K3b: act[slot][f] = tw * silu(g0+g1) * (u0+u1) ----------------
// grid 8192 blocks x 128 thr; thread handles 4 consecutive f.
__global__ __launch_bounds__(128) void k_act(
    const u16* __restrict__ pbuf, const float* __restrict__ sw,
    u16* __restrict__ act)
{
  const int gs = blockIdx.x;
  const int f = threadIdx.x * 4;
  const float tw = sw[gs];
  const u16* p0 = pbuf + (size_t)gs*1024;
  const u16* p1 = p0 + (size_t)8192*1024;
  const u16x4 g0 = *(const u16x4*)(p0 + f);
  const u16x4 g1 = *(const u16x4*)(p1 + f);
  const u16x4 u0 = *(const u16x4*)(p0 + 512 + f);
  const u16x4 u1 = *(const u16x4*)(p1 + 512 + f);
  u16x4 o;
  #pragma unroll
  for (int j = 0; j < 4; ++j){
    const float g = b2f(g0[j]) + b2f(g1[j]);
    const float u = b2f(u0[j]) + b2f(u1[j]);
    const float a = tw * (g / (1.f + __expf(-g))) * u;
    o[j] = f2bf(a);
  }
  *(u16x4*)(act + (size_t)gs*F_ + f) = o;
}

// ---------------- K4: down GEMM (256x128 tile, BK=32, fused W staging), bf16 -> ydown ----------------
// grid 2048: bid = tt*256 + e*16 + dt (tt slowest). 512 thr / 8 waves (4 tm x 2 dh), acc 4x4. 64KB LDS.
__global__ __launch_bounds__(512, 4) void k_down(
    const u16* __restrict__ act, const float* __restrict__ wd,
    const int* __restrict__ counts, u16* __restrict__ ydown)
{
  const int bid = blockIdx.x;
  const int tt = bid >> 8;
  const int e  = (bid >> 4) & 15;
  const int dt = bid & 15;

  const int cnt = counts[e], row0 = tt * 256;
  if (row0 >= cnt) return;
  int abase = 0;
  for (int i = 0; i < e; ++i) abase += counts[i];

  const int tid = threadIdx.x, lane = tid & 63, w = tid >> 6;
  const int d0 = dt * 128;

  __shared__ __align__(16) u16 As[3][8192];   // [stage][256 rows x 32 k] 16KB
  __shared__ __align__(16) u16 Wd[2][4096];   // [buf][128 d-rows x 32 k] 8KB

  const int lr = lane >> 2, lc = lane & 3;
  const int csw = lc ^ (lr & 3) ^ ((lr >> 2) & 3);
  const u16* srcX[2]; u32 dof[2];
  #pragma unroll
  for (int q = 0; q < 2; ++q){
    const int r = w*32 + q*16 + lr;
    const int rs = (row0 + r < cnt) ? (row0 + r) : (cnt - 1);
    srcX[q] = act + (size_t)(abase + rs)*F_ + 8*csw;
    dof[q] = (u32)((w*32 + q*16) * 32);
  }
  const int rg4 = tid & 31, ko = tid >> 5;   // ko 0..15 -> k pair
  const float* srcWf = wd + (size_t)e*F_*D_ + d0 + rg4*4;

  const int p = lane & 15, g4 = lane >> 4;
  const int tm = w >> 1, dh = w & 1;
  u32 aB[4], bB[4];
  #pragma unroll
  for (int m = 0; m < 4; ++m) aB[m] = (u32)((tm*64 + m*16 + p) * 32);
  #pragma unroll
  for (int n = 0; n < 4; ++n) bB[n] = (u32)((dh*64 + n*16 + p) * 32);
  const u32 s8 = 8u * (u32)(g4 ^ (p & 3) ^ ((p >> 2) & 3));

  f32x4 acc[4][4] = {};
  float wvf[4][2];

  // prologue: W0(2); X0(2); X1(2); vmcnt(4) retires W0; store; vmcnt(2) retires X0.
  WLOADD(0, srcWf, D_);
  #pragma unroll
  for (int q = 0; q < 2; ++q) gload16(srcX[q],      (void*)&As[0][dof[q]]);
  #pragma unroll
  for (int q = 0; q < 2; ++q) gload16(srcX[q] + 32, (void*)&As[1][dof[q]]);
  asm volatile("s_waitcnt vmcnt(4)" ::: "memory");
  __builtin_amdgcn_sched_barrier(0);
  WSTORED(&Wd[0][0]);
  asm volatile("s_waitcnt vmcnt(2)" ::: "memory");

  const int NSTEP = F_ / 32;   // 16
  int xc = 0;
  for (int kt = 0; kt < NSTEP; ++kt){
    asm volatile("s_waitcnt lgkmcnt(0)" ::: "memory");
    __builtin_amdgcn_s_barrier();
    __builtin_amdgcn_sched_barrier(0);
    if (kt + 1 < NSTEP){
      WLOADD((kt + 1) * 32, srcWf, D_);
      __builtin_amdgcn_sched_barrier(0);
    }
    {
      const u16* Ap = &As[xc][0];
      const u16* Wp = &Wd[kt & 1][0];
      bf16x8 aF[4], bF[4];
      #pragma unroll
      for (int m = 0; m < 4; ++m) aF[m] = *(const bf16x8*)&Ap[aB[m] + s8];
      #pragma unroll
      for (int n = 0; n < 4; ++n) bF[n] = *(const bf16x8*)&Wp[bB[n] + s8];
      #pragma unroll
      for (int m = 0; m < 4; ++m)
        #pragma unroll
        for (int n = 0; n < 4; ++n)
          acc[m][n] = __builtin_amdgcn_mfma_f32_16x16x32_bf16(aF[m], bF[n], acc[m][n], 0, 0, 0);
    }
    if (kt + 2 < NSTEP){
      const int kb2 = (kt + 2) * 32;
      int nb = xc + 2; if (nb >= 3) nb -= 3;
      #pragma unroll
      for (int q = 0; q < 2; ++q) gload16(srcX[q] + kb2, (void*)&As[nb][dof[q]]);
    }
    if (kt + 1 < NSTEP){
      if (kt + 2 < NSTEP) asm volatile("s_waitcnt vmcnt(2)" ::: "memory");
      else                asm volatile("s_waitcnt vmcnt(0)" ::: "memory");
      __builtin_amdgcn_sched_barrier(0);
      WSTORED(&Wd[(kt + 1) & 1][0]);
    }
    xc = (xc == 2) ? 0 : xc + 1;
  }

  #pragma unroll
  for (int m = 0; m < 4; ++m){
    #pragma unroll
    for (int r = 0; r < 4; ++r){
      const int row  = tm*64 + m*16 + g4*4 + r;
      const int slot = row0 + row;
      if (slot < cnt){
        u16* yp = ydown + (size_t)(abase + slot)*D_ + d0 + dh*64;
        #pragma unroll
        for (int n = 0; n < 4; ++n)
          yp[n*16 + p] = f2bf(acc[m][n][r]);
      }
    }
  }
}

// ---------------- K5: combine: out = x + sum_k ydown[slot_k(t)] ----------------
__global__ __launch_bounds__(256) void k_combine(
    const float* __restrict__ x, const u16* __restrict__ ydown,
    const int* __restrict__ tok_slot, float* __restrict__ out)
{
  const int t = blockIdx.x;
  const int d0 = threadIdx.x * 8;
  const int4 sl = *(const int4*)(tok_slot + t*4);
  const float4 x0 = *(const float4*)(x + (size_t)t*D_ + d0);
  const float4 x1 = *(const float4*)(x + (size_t)t*D_ + d0 + 4);
  float s[8] = {x0.x, x0.y, x0.z, x0.w, x1.x, x1.y, x1.z, x1.w};
  const int sls[4] = {sl.x, sl.y, sl.z, sl.w};
  #pragma unroll
  for (int k = 0; k < 4; ++k){
    const u16x8 v = *(const u16x8*)(ydown + (size_t)sls[k]*D_ + d0);
    #pragma unroll
    for (int j = 0; j < 8; ++j){
      union { u32 u; float f; } c; c.u = (u32)v[j] << 16;
      s[j] += c.f;
    }
  }
  float4 o0 = {s[0], s[1], s[2], s[3]};
  float4 o1 = {s[4], s[5], s[6], s[7]};
  *(float4*)(out + (size_t)t*D_ + d0)     = o0;
  *(float4*)(out + (size_t)t*D_ + d0 + 4) = o1;
}

extern "C" void kernel_launch(void* const* d_in, const int* in_sizes, int n_in,
                              void* d_out, int out_size, void* d_ws, size_t ws_size,
                              hipStream_t stream)
{
  (void)in_sizes; (void)n_in; (void)out_size; (void)ws_size;
  const float* x     = (const float*)d_in[0];
  const float* nw    = (const float*)d_in[1];
  const float* gw    = (const float*)d_in[2];
  const float* wgate = (const float*)d_in[3];
  const float* wup   = (const float*)d_in[4];
  const float* wdown = (const float*)d_in[5];
  float* out = (float*)d_out;

  char* ws = (char*)d_ws;
  u16*   h        = (u16*)(ws);                     // 8,388,608 B
  u16*   act      = (u16*)(ws + 8388608);           // 8,519,680 B
  int*   counts   = (int*)(ws + 16908288);          // 64 B
  int*   eidx     = (int*)(ws + 16908352);          // 131,072 B
  float* ew       = (float*)(ws + 17039424);        // 131,072 B
  int*   tok_e    = (int*)(ws + 17170496);          // 32,768 B
  float* tok_w    = (float*)(ws + 17203264);        // 32,768 B
  int*   tok_slot = (int*)(ws + 17236032);          // 32,768 B
  float* sw       = (float*)(ws + 17268800);        // 32,768 B
  u16*   ydown    = (u16*)(ws + 17301568);          // 33,554,432 B [8192][2048] bf16
  u16*   pbuf     = (u16*)(ws + 50856000);          // 33,554,432 B [2][8192][1024] bf16

  k_norm_router<<<T_, 256, 0, stream>>>(x, nw, gw, h, tok_e, tok_w);
  k_build_lists<<<E_, 256, 0, stream>>>(tok_e, tok_w, eidx, ew, counts);
  k_slots<<<E_, 256, 0, stream>>>(counts, eidx, ew, tok_e, tok_slot, sw);
  k_gateup<<<2048, 256, 0, stream>>>(h, wgate, wup, counts, eidx, pbuf);
  k_act<<<8192, 128, 0, stream>>>(pbuf, sw, act);
  k_down<<<2048, 512, 0, stream>>>(act, wdown, counts, ydown);
  k_combine<<<T_, 256, 0, stream>>>(x, ydown, tok_slot, out);
}

// Round 25
// 170.656 us; speedup vs baseline: 1.1202x; 1.1202x over previous
//
#include <hip/hip_runtime.h>
#include <cstdint>
#include <cstddef>

#define T_ 2048
#define D_ 2048
#define E_ 16
#define F_ 512

typedef unsigned short u16;
typedef unsigned int u32;
typedef unsigned long long u64;
typedef __attribute__((ext_vector_type(8))) short bf16x8;
typedef __attribute__((ext_vector_type(4))) float f32x4;
typedef __attribute__((ext_vector_type(2))) u32 u32x2;
typedef __attribute__((ext_vector_type(4))) u32 u32x4;
typedef __attribute__((ext_vector_type(8))) u16 u16x8;

__device__ __forceinline__ u16 f2bf(float f){
  union { float f; u32 u; } c; c.f = f;
  return (u16)((c.u + 0x7FFFu + ((c.u >> 16) & 1u)) >> 16);
}

__device__ __forceinline__ void gload16(const void* g, void* l){
  __builtin_amdgcn_global_load_lds((const __attribute__((address_space(1))) void*)g,
                                   (__attribute__((address_space(3))) void*)l,
                                   16, 0, 0);
}

__device__ __forceinline__ u32 pk2(float a, float b){
  u32 r;
  asm("v_cvt_pk_bf16_f32 %0, %1, %2" : "=v"(r) : "v"(a), "v"(b));
  return r;
}

// ---------------- K1: rmsnorm + router (fp32); writes per-token top4 ----------------
__global__ __launch_bounds__(256) void k_norm_router(
    const float* __restrict__ x, const float* __restrict__ nw, const float* __restrict__ gw,
    u16* __restrict__ h, int* __restrict__ tok_e, float* __restrict__ tok_w)
{
  const int t = blockIdx.x, tid = threadIdx.x;
  const int lane = tid & 63, wid = tid >> 6;
  const int d0 = tid * 8;
  const float4 v0 = *(const float4*)(x + (size_t)t*D_ + d0);
  const float4 v1 = *(const float4*)(x + (size_t)t*D_ + d0 + 4);
  float hv[8] = {v0.x, v0.y, v0.z, v0.w, v1.x, v1.y, v1.z, v1.w};
  float ss = 0.f;
  #pragma unroll
  for (int j = 0; j < 8; ++j) ss += hv[j]*hv[j];
  #pragma unroll
  for (int o = 32; o; o >>= 1) ss += __shfl_xor(ss, o);
  __shared__ float sred[4];
  __shared__ float red16[4][16];
  __shared__ float lf[16];
  if (lane == 0) sred[wid] = ss;
  __syncthreads();
  const float rstd = rsqrtf((sred[0]+sred[1]+sred[2]+sred[3]) * (1.f/(float)D_) + 1e-6f);
  const float4 w0 = *(const float4*)(nw + d0);
  const float4 w1 = *(const float4*)(nw + d0 + 4);
  const float wv[8] = {w0.x,w0.y,w0.z,w0.w,w1.x,w1.y,w1.z,w1.w};
  #pragma unroll
  for (int j = 0; j < 8; ++j) hv[j] = hv[j] * rstd * wv[j];
  u16x8 hb;
  #pragma unroll
  for (int j = 0; j < 8; ++j) hb[j] = f2bf(hv[j]);
  *(u16x8*)(h + (size_t)t*D_ + d0) = hb;

  float lg[16];
  #pragma unroll
  for (int e = 0; e < 16; ++e){
    const float4 g0 = *(const float4*)(gw + e*D_ + d0);
    const float4 g1 = *(const float4*)(gw + e*D_ + d0 + 4);
    lg[e] = hv[0]*g0.x + hv[1]*g0.y + hv[2]*g0.z + hv[3]*g0.w
          + hv[4]*g1.x + hv[5]*g1.y + hv[6]*g1.z + hv[7]*g1.w;
  }
  #pragma unroll
  for (int e = 0; e < 16; ++e){
    #pragma unroll
    for (int o = 32; o; o >>= 1) lg[e] += __shfl_xor(lg[e], o);
  }
  if (lane == 0){
    #pragma unroll
    for (int e = 0; e < 16; ++e) red16[wid][e] = lg[e];
  }
  __syncthreads();
  if (tid < 16) lf[tid] = red16[0][tid] + red16[1][tid] + red16[2][tid] + red16[3][tid];
  __syncthreads();
  if (tid == 0){
    float l[16];
    #pragma unroll
    for (int e = 0; e < 16; ++e) l[e] = lf[e];
    int sel[4]; float sv[4]; u32 used = 0;
    for (int k = 0; k < 4; ++k){
      float b = -3.4e38f; int bi = 0;
      for (int e = 0; e < 16; ++e)
        if (!((used >> e) & 1u) && l[e] > b){ b = l[e]; bi = e; }
      used |= 1u << bi; sel[k] = bi; sv[k] = b;
    }
    float ex[4]; float s = 0.f;
    for (int k = 0; k < 4; ++k){ ex[k] = __expf(sv[k] - sv[0]); s += ex[k]; }
    const float inv = 1.f / s;
    int4 te = {sel[0], sel[1], sel[2], sel[3]};
    float4 tw4 = {ex[0]*inv, ex[1]*inv, ex[2]*inv, ex[3]*inv};
    *(int4*)(tok_e + t*4) = te;
    *(float4*)(tok_w + t*4) = tw4;
  }
}

// ---------------- K2: build per-expert token lists (deterministic compaction) ----------------
__global__ __launch_bounds__(256) void k_build_lists(
    const int* __restrict__ tok_e, const float* __restrict__ tok_w,
    int* __restrict__ eidx, float* __restrict__ ew, int* __restrict__ counts)
{
  const int e = blockIdx.x, tid = threadIdx.x;
  const int lane = tid & 63, wid = tid >> 6;
  __shared__ int wtot[4];
  __shared__ int base;
  if (tid == 0) base = 0;
  __syncthreads();
  for (int t0 = 0; t0 < T_; t0 += 256){
    const int t = t0 + tid;
    const int4 te = *(const int4*)(tok_e + t*4);
    const float4 tw = *(const float4*)(tok_w + t*4);
    bool m = false; float wv = 0.f;
    if      (te.x == e){ m = true; wv = tw.x; }
    else if (te.y == e){ m = true; wv = tw.y; }
    else if (te.z == e){ m = true; wv = tw.z; }
    else if (te.w == e){ m = true; wv = tw.w; }
    const u64 mask = __ballot(m);
    const int pre = __popcll(mask & ((1ull << lane) - 1ull));
    if (lane == 0) wtot[wid] = __popcll(mask);
    __syncthreads();
    int wbase = base;
    for (int i = 0; i < wid; ++i) wbase += wtot[i];
    if (m){
      eidx[e*T_ + wbase + pre] = t;
      ew[e*T_ + wbase + pre] = wv;
    }
    __syncthreads();
    if (tid == 0) base += wtot[0] + wtot[1] + wtot[2] + wtot[3];
    __syncthreads();
  }
  if (tid == 0) counts[e] = base;
}

// ---------------- K2b: invert lists -> per-token slot ids ----------------
__global__ __launch_bounds__(256) void k_slots(
    const int* __restrict__ counts, const int* __restrict__ eidx,
    const int* __restrict__ tok_e, int* __restrict__ tok_slot)
{
  const int e = blockIdx.x;
  int abase = 0;
  for (int i = 0; i < e; ++i) abase += counts[i];
  const int cnt = counts[e];
  for (int s = threadIdx.x; s < cnt; s += 256){
    const int t = eidx[e*T_ + s];
    const int4 te = *(const int4*)(tok_e + t*4);
    const int kidx = (te.x == e) ? 0 : (te.y == e) ? 1 : (te.z == e) ? 2 : 3;
    tok_slot[t*4 + kidx] = abase + s;
  }
}

// -------- gateup W staging: thread -> 4 rows x 4 k (one float4 per k) --------
#define WLOADG(KB, SRC, S) do {                                                \
    _Pragma("unroll")                                                          \
    for (int j = 0; j < 4; ++j){                                               \
      const float4 t_ = *(const float4*)((SRC) + (size_t)((KB) + ko*4 + j)*(S));\
      wvf[0][j]=t_.x; wvf[1][j]=t_.y; wvf[2][j]=t_.z; wvf[3][j]=t_.w;          \
    }                                                                          \
  } while (0)

#define WSTOREG(WP) do {                                                       \
    _Pragma("unroll")                                                          \
    for (int i = 0; i < 4; ++i){                                               \
      const int r_ = rg4*4 + i;                                                \
      const u32 idx_ = (u32)(r_*32 + ((ko>>1) ^ (r_&3) ^ ((r_>>2)&3))*8 + (ko&1)*4); \
      u32x2 o_ = { pk2(wvf[i][0], wvf[i][1]), pk2(wvf[i][2], wvf[i][3]) };     \
      *(u32x2*)&(WP)[idx_] = o_;                                               \
    }                                                                          \
  } while (0)

// -------- down W staging: thread -> 4 rows x 2 k --------
#define WLOADD(KB, SRC, S) do {                                                \
    _Pragma("unroll")                                                          \
    for (int j = 0; j < 2; ++j){                                               \
      const float4 t_ = *(const float4*)((SRC) + (size_t)((KB) + ko*2 + j)*(S));\
      wvf[0][j]=t_.x; wvf[1][j]=t_.y; wvf[2][j]=t_.z; wvf[3][j]=t_.w;          \
    }                                                                          \
  } while (0)

#define WSTORED(WP) do {                                                       \
    _Pragma("unroll")                                                          \
    for (int i = 0; i < 4; ++i){                                               \
      const int r_ = rg4*4 + i;                                                \
      const u32 idx_ = (u32)(r_*32 + ((ko>>2) ^ (r_&3) ^ ((r_>>2)&3))*8 + (ko&3)*2); \
      *(u32*)&(WP)[idx_] = pk2(wvf[i][0], wvf[i][1]);                          \
    }                                                                          \
  } while (0)

// ---------------- K3: gate/up GEMM + silu*up (256 tok x 64F tile, BK=32, fused W staging) ----------------
// grid 1024: bid = tt*128 + e*8 + ft (tt slowest). 256 thr / 4 waves, wave 64x128, acc 4x8. 64KB LDS.
__global__ __launch_bounds__(256, 2) void k_gateup(
    const u16* __restrict__ h, const float* __restrict__ wg, const float* __restrict__ wu,
    const int* __restrict__ counts, const int* __restrict__ eidx, const float* __restrict__ ew,
    u16* __restrict__ act)
{
  const int bid = blockIdx.x;
  const int tt = bid >> 7;
  const int e  = (bid >> 3) & 15;
  const int ft = bid & 7;

  const int cnt = counts[e];
  const int row0 = tt * 256;
  if (row0 >= cnt) return;
  int abase = 0;
  for (int i = 0; i < e; ++i) abase += counts[i];

  const int tid = threadIdx.x, lane = tid & 63, w = tid >> 6;
  const int f0 = ft * 64;

  __shared__ __align__(16) u16 Xs[3][8192];   // [stage][256 rows x 32 k] 16KB each
  __shared__ __align__(16) u16 Ws[2][4096];   // [buf][rows 0..63 gate, 64..127 up] 8KB each

  int* toksS = (int*)&Xs[0][0];
  if (tid < 256){
    const int slot = row0 + tid;
    const int cs = slot < cnt ? slot : (cnt - 1);
    toksS[tid] = eidx[e*T_ + cs];
  }
  __syncthreads();

  // X staging: wave w stages rows [w*64, +64); 4 instr x 16 rows; lane -> row lane>>2, chunk lane&3
  const int lr = lane >> 2, lc = lane & 3;
  const int csw = lc ^ (lr & 3) ^ ((lr >> 2) & 3);
  const u16* srcX[4]; u32 dof[4];
  #pragma unroll
  for (int q = 0; q < 4; ++q){
    const int r = w*64 + q*16 + lr;
    srcX[q] = h + (size_t)toksS[r]*D_ + 8*csw;
    dof[q] = (u32)((w*64 + q*16) * 32);
  }
  // W staging: rg4 = tid&31 -> rows rg4*4..+3 (gate rg4<16, else up); ko = tid>>5 (0..7) -> 4 k's
  const int rg4 = tid & 31, ko = tid >> 5;
  const float* wsel = (rg4 < 16) ? wg : wu;
  const float* srcWf = wsel + (size_t)e*D_*F_ + f0 + ((rg4*4) & 63);
  __syncthreads();   // done with toks overlay

  const int p = lane & 15, g4 = lane >> 4;
  u32 aB[4], bB[8];
  #pragma unroll
  for (int m = 0; m < 4; ++m) aB[m] = (u32)((w*64 + m*16 + p) * 32);
  #pragma unroll
  for (int n = 0; n < 8; ++n) bB[n] = (u32)((n*16 + p) * 32);
  const u32 s8 = 8u * (u32)(g4 ^ (p & 3) ^ ((p >> 2) & 3));

  f32x4 acc[4][8] = {};
  float wvf[4][4];

  // prologue: W0(4); X0(4); X1(4); vmcnt(8) retires W0; store W0; vmcnt(4) retires X0.
  WLOADG(0, srcWf, F_);
  #pragma unroll
  for (int q = 0; q < 4; ++q) gload16(srcX[q],      (void*)&Xs[0][dof[q]]);
  #pragma unroll
  for (int q = 0; q < 4; ++q) gload16(srcX[q] + 32, (void*)&Xs[1][dof[q]]);
  asm volatile("s_waitcnt vmcnt(8)" ::: "memory");
  __builtin_amdgcn_sched_barrier(0);
  WSTOREG(&Ws[0][0]);
  asm volatile("s_waitcnt vmcnt(4)" ::: "memory");

  const int NSTEP = D_ / 32;   // 64
  int xc = 0;
  for (int kt = 0; kt < NSTEP; ++kt){
    asm volatile("s_waitcnt lgkmcnt(0)" ::: "memory");
    __builtin_amdgcn_s_barrier();
    __builtin_amdgcn_sched_barrier(0);
    if (kt + 1 < NSTEP){
      WLOADG((kt + 1) * 32, srcWf, F_);
      __builtin_amdgcn_sched_barrier(0);
    }
    {
      const u16* Xp = &Xs[xc][0];
      const u16* Wp = &Ws[kt & 1][0];
      bf16x8 aF[4], bF[8];
      #pragma unroll
      for (int m = 0; m < 4; ++m) aF[m] = *(const bf16x8*)&Xp[aB[m] + s8];
      #pragma unroll
      for (int n = 0; n < 8; ++n) bF[n] = *(const bf16x8*)&Wp[bB[n] + s8];
      #pragma unroll
      for (int m = 0; m < 4; ++m)
        #pragma unroll
        for (int n = 0; n < 8; ++n)
          acc[m][n] = __builtin_amdgcn_mfma_f32_16x16x32_bf16(aF[m], bF[n], acc[m][n], 0, 0, 0);
    }
    if (kt + 2 < NSTEP){
      const int kb2 = (kt + 2) * 32;
      int nb = xc + 2; if (nb >= 3) nb -= 3;
      #pragma unroll
      for (int q = 0; q < 4; ++q) gload16(srcX[q] + kb2, (void*)&Xs[nb][dof[q]]);
    }
    if (kt + 1 < NSTEP){
      if (kt + 2 < NSTEP) asm volatile("s_waitcnt vmcnt(4)" ::: "memory");
      else                asm volatile("s_waitcnt vmcnt(0)" ::: "memory");
      __builtin_amdgcn_sched_barrier(0);
      WSTOREG(&Ws[(kt + 1) & 1][0]);
    }
    xc = (xc == 2) ? 0 : xc + 1;
  }

  #pragma unroll
  for (int m = 0; m < 4; ++m)
    #pragma unroll
    for (int r = 0; r < 4; ++r){
      const int row  = w*64 + m*16 + g4*4 + r;
      const int slot = row0 + row;
      if (slot < cnt){
        const float tw = ew[e*T_ + slot];
        #pragma unroll
        for (int n = 0; n < 4; ++n){
          const float gv = acc[m][n][r], uv = acc[m][n+4][r];
          const float a = tw * (gv / (1.f + __expf(-gv))) * uv;
          act[(size_t)(abase + slot)*F_ + f0 + n*16 + p] = f2bf(a);
        }
      }
    }
}

// ---------------- K4: down GEMM (256x128 tile, BK=32, fused W staging), bf16 -> ydown ----------------
// grid 2048: bid = tt*256 + e*16 + dt (tt slowest). 512 thr / 8 waves (4 tm x 2 dh), acc 4x4. 64KB LDS.
__global__ __launch_bounds__(512, 4) void k_down(
    const u16* __restrict__ act, const float* __restrict__ wd,
    const int* __restrict__ counts, u16* __restrict__ ydown)
{
  const int bid = blockIdx.x;
  const int tt = bid >> 8;
  const int e  = (bid >> 4) & 15;
  const int dt = bid & 15;

  const int cnt = counts[e], row0 = tt * 256;
  if (row0 >= cnt) return;
  int abase = 0;
  for (int i = 0; i < e; ++i) abase += counts[i];

  const int tid = threadIdx.x, lane = tid & 63, w = tid >> 6;
  const int d0 = dt * 128;

  __shared__ __align__(16) u16 As[3][8192];   // [stage][256 rows x 32 k] 16KB
  __shared__ __align__(16) u16 Wd[2][4096];   // [buf][128 d-rows x 32 k] 8KB

  const int lr = lane >> 2, lc = lane & 3;
  const int csw = lc ^ (lr & 3) ^ ((lr >> 2) & 3);
  const u16* srcX[2]; u32 dof[2];
  #pragma unroll
  for (int q = 0; q < 2; ++q){
    const int r = w*32 + q*16 + lr;
    const int rs = (row0 + r < cnt) ? (row0 + r) : (cnt - 1);
    srcX[q] = act + (size_t)(abase + rs)*F_ + 8*csw;
    dof[q] = (u32)((w*32 + q*16) * 32);
  }
  const int rg4 = tid & 31, ko = tid >> 5;   // ko 0..15 -> k pair
  const float* srcWf = wd + (size_t)e*F_*D_ + d0 + rg4*4;

  const int p = lane & 15, g4 = lane >> 4;
  const int tm = w >> 1, dh = w & 1;
  u32 aB[4], bB[4];
  #pragma unroll
  for (int m = 0; m < 4; ++m) aB[m] = (u32)((tm*64 + m*16 + p) * 32);
  #pragma unroll
  for (int n = 0; n < 4; ++n) bB[n] = (u32)((dh*64 + n*16 + p) * 32);
  const u32 s8 = 8u * (u32)(g4 ^ (p & 3) ^ ((p >> 2) & 3));

  f32x4 acc[4][4] = {};
  float wvf[4][2];

  // prologue: W0(2); X0(2); X1(2); vmcnt(4) retires W0; store; vmcnt(2) retires X0.
  WLOADD(0, srcWf, D_);
  #pragma unroll
  for (int q = 0; q < 2; ++q) gload16(srcX[q],      (void*)&As[0][dof[q]]);
  #pragma unroll
  for (int q = 0; q < 2; ++q) gload16(srcX[q] + 32, (void*)&As[1][dof[q]]);
  asm volatile("s_waitcnt vmcnt(4)" ::: "memory");
  __builtin_amdgcn_sched_barrier(0);
  WSTORED(&Wd[0][0]);
  asm volatile("s_waitcnt vmcnt(2)" ::: "memory");

  const int NSTEP = F_ / 32;   // 16
  int xc = 0;
  for (int kt = 0; kt < NSTEP; ++kt){
    asm volatile("s_waitcnt lgkmcnt(0)" ::: "memory");
    __builtin_amdgcn_s_barrier();
    __builtin_amdgcn_sched_barrier(0);
    if (kt + 1 < NSTEP){
      WLOADD((kt + 1) * 32, srcWf, D_);
      __builtin_amdgcn_sched_barrier(0);
    }
    {
      const u16* Ap = &As[xc][0];
      const u16* Wp = &Wd[kt & 1][0];
      bf16x8 aF[4], bF[4];
      #pragma unroll
      for (int m = 0; m < 4; ++m) aF[m] = *(const bf16x8*)&Ap[aB[m] + s8];
      #pragma unroll
      for (int n = 0; n < 4; ++n) bF[n] = *(const bf16x8*)&Wp[bB[n] + s8];
      #pragma unroll
      for (int m = 0; m < 4; ++m)
        #pragma unroll
        for (int n = 0; n < 4; ++n)
          acc[m][n] = __builtin_amdgcn_mfma_f32_16x16x32_bf16(aF[m], bF[n], acc[m][n], 0, 0, 0);
    }
    if (kt + 2 < NSTEP){
      const int kb2 = (kt + 2) * 32;
      int nb = xc + 2; if (nb >= 3) nb -= 3;
      #pragma unroll
      for (int q = 0; q < 2; ++q) gload16(srcX[q] + kb2, (void*)&As[nb][dof[q]]);
    }
    if (kt + 1 < NSTEP){
      if (kt + 2 < NSTEP) asm volatile("s_waitcnt vmcnt(2)" ::: "memory");
      else                asm volatile("s_waitcnt vmcnt(0)" ::: "memory");
      __builtin_amdgcn_sched_barrier(0);
      WSTORED(&Wd[(kt + 1) & 1][0]);
    }
    xc = (xc == 2) ? 0 : xc + 1;
  }

  #pragma unroll
  for (int m = 0; m < 4; ++m){
    #pragma unroll
    for (int r = 0; r < 4; ++r){
      const int row  = tm*64 + m*16 + g4*4 + r;
      const int slot = row0 + row;
      if (slot < cnt){
        u16* yp = ydown + (size_t)(abase + slot)*D_ + d0 + dh*64;
        #pragma unroll
        for (int n = 0; n < 4; ++n)
          yp[n*16 + p] = f2bf(acc[m][n][r]);
      }
    }
  }
}

// ---------------- K5: combine: out = x + sum_k ydown[slot_k(t)] ----------------
__global__ __launch_bounds__(256) void k_combine(
    const float* __restrict__ x, const u16* __restrict__ ydown,
    const int* __restrict__ tok_slot, float* __restrict__ out)
{
  const int t = blockIdx.x;
  const int d0 = threadIdx.x * 8;
  const int4 sl = *(const int4*)(tok_slot + t*4);
  const float4 x0 = *(const float4*)(x + (size_t)t*D_ + d0);
  const float4 x1 = *(const float4*)(x + (size_t)t*D_ + d0 + 4);
  float s[8] = {x0.x, x0.y, x0.z, x0.w, x1.x, x1.y, x1.z, x1.w};
  const int sls[4] = {sl.x, sl.y, sl.z, sl.w};
  #pragma unroll
  for (int k = 0; k < 4; ++k){
    const u16x8 v = *(const u16x8*)(ydown + (size_t)sls[k]*D_ + d0);
    #pragma unroll
    for (int j = 0; j < 8; ++j){
      union { u32 u; float f; } c; c.u = (u32)v[j] << 16;
      s[j] += c.f;
    }
  }
  float4 o0 = {s[0], s[1], s[2], s[3]};
  float4 o1 = {s[4], s[5], s[6], s[7]};
  *(float4*)(out + (size_t)t*D_ + d0)     = o0;
  *(float4*)(out + (size_t)t*D_ + d0 + 4) = o1;
}

extern "C" void kernel_launch(void* const* d_in, const int* in_sizes, int n_in,
                              void* d_out, int out_size, void* d_ws, size_t ws_size,
                              hipStream_t stream)
{
  (void)in_sizes; (void)n_in; (void)out_size; (void)ws_size;
  const float* x     = (const float*)d_in[0];
  const float* nw    = (const float*)d_in[1];
  const float* gw    = (const float*)d_in[2];
  const float* wgate = (const float*)d_in[3];
  const float* wup   = (const float*)d_in[4];
  const float* wdown = (const float*)d_in[5];
  float* out = (float*)d_out;

  char* ws = (char*)d_ws;
  u16*   h        = (u16*)(ws);                     // 8,388,608 B
  u16*   act      = (u16*)(ws + 8388608);           // 8,519,680 B
  int*   counts   = (int*)(ws + 16908288);          // 64 B
  int*   eidx     = (int*)(ws + 16908352);          // 131,072 B
  float* ew       = (float*)(ws + 17039424);        // 131,072 B
  int*   tok_e    = (int*)(ws + 17170496);          // 32,768 B
  float* tok_w    = (float*)(ws + 17203264);        // 32,768 B
  int*   tok_slot = (int*)(ws + 17236032);          // 32,768 B
  u16*   ydown    = (u16*)(ws + 17268800);          // 33,554,432 B [8192][2048] bf16

  k_norm_router<<<T_, 256, 0, stream>>>(x, nw, gw, h, tok_e, tok_w);
  k_build_lists<<<E_, 256, 0, stream>>>(tok_e, tok_w, eidx, ew, counts);
  k_slots<<<E_, 256, 0, stream>>>(counts, eidx, tok_e, tok_slot);
  k_gateup<<<1024, 256, 0, stream>>>(h, wgate, wup, counts, eidx, ew, act);
  k_down<<<2048, 512, 0, stream>>>(act, wdown, counts, ydown);
  k_combine<<<T_, 256, 0, stream>>>(x, ydown, tok_slot, out);
}